// Round 1
// baseline (738.344 us; speedup 1.0000x reference)
//
#include <hip/hip_runtime.h>
#include <hip/hip_bf16.h>

#define K_CODES 8192
#define DIM     512
#define N_VEC   32768
#define MARGIN  0.35f   // flag threshold on g = x.e - e2/2 ; ~10 sigma of bf16 error

typedef __attribute__((ext_vector_type(8))) short   short8;   // bf16x8 MFMA operand
typedef __attribute__((ext_vector_type(8))) unsigned short ushort8;
typedef __attribute__((ext_vector_type(4))) float   float4x;  // MFMA C/D frag

// async global->LDS, 16 B/lane. LDS dest = wave-uniform base + lane*16.
__device__ inline void gl_lds16(const void* g, void* l) {
    __builtin_amdgcn_global_load_lds(
        (const __attribute__((address_space(1))) unsigned int*)g,
        (__attribute__((address_space(3))) unsigned int*)l, 16, 0, 0);
}

// fp32 -> bf16 bits, round-to-nearest-even
__device__ inline unsigned short f2bf(float f) {
    unsigned int u = __float_as_uint(f);
    return (unsigned short)((u + 0x7FFFu + ((u >> 16) & 1u)) >> 16);
}

// ---------------------------------------------------------------------------
// Kernel 1: prep. rows [0,N_VEC) from z -> zh + x2 ; rows [N_VEC,+K) from cb
// -> ch + hne2 = -0.5*||e||^2.  One wave per row.
// ---------------------------------------------------------------------------
__global__ __launch_bounds__(256) void vq_prep(
    const float* __restrict__ z, const float* __restrict__ cb,
    float* __restrict__ x2, float* __restrict__ hne2,
    unsigned short* __restrict__ zh, unsigned short* __restrict__ ch) {
    int wave = threadIdx.x >> 6;
    int lane = threadIdx.x & 63;
    int row  = blockIdx.x * 4 + wave;
    bool isZ = row < N_VEC;
    int lr = isZ ? row : row - N_VEC;
    const float* src = isZ ? z + (size_t)row * DIM : cb + (size_t)lr * DIM;

    const float4* s4 = (const float4*)src;
    float4 v0 = s4[lane * 2];
    float4 v1 = s4[lane * 2 + 1];
    float f[8] = {v0.x, v0.y, v0.z, v0.w, v1.x, v1.y, v1.z, v1.w};

    float s = 0.0f;
    ushort8 h8;
#pragma unroll
    for (int i = 0; i < 8; ++i) { s += f[i] * f[i]; h8[i] = f2bf(f[i]); }
    ((ushort8*)(isZ ? zh : ch))[(size_t)lr * 64 + lane] = h8;

#pragma unroll
    for (int off = 32; off >= 1; off >>= 1) s += __shfl_xor(s, off, 64);
    if (lane == 0) {
        if (isZ) x2[lr] = s;
        else     hne2[lr] = -0.5f * s;
    }
}

// ---------------------------------------------------------------------------
// Kernel 2: bf16 MFMA GEMM + fused TOP-3 (values) / TOP-2 (indices) of
// g = x.e - e2/2.  Block = 128 rows x 4096 codes (half=blockIdx.y), 16 tiles
// of 256 codes.  4 waves in 2x2 (wM x wN); per-wave 64x128 tile.
// Partials written RACE-FREE to slot = half*2 + wN (4 slots per row).
// n1|n2 packed 16+16 in one reg to limit unified-register growth.
// ---------------------------------------------------------------------------
__global__ __launch_bounds__(256, 2) void vq_gemm(
    const unsigned short* __restrict__ zh, const unsigned short* __restrict__ ch,
    const float* __restrict__ hne2,
    float* __restrict__ pG, int* __restrict__ pN, float* __restrict__ pG2,
    int* __restrict__ pN2, float* __restrict__ pG3) {
    __shared__ short8 AsC[1024];   // 128 rows x 8 octet-cells, XOR-swizzled (16 KB)
    __shared__ short8 BsC[2048];   // 256 codes x 8 octet-cells, XOR-swizzled (32 KB)

    const int tid  = threadIdx.x;
    const int w    = tid >> 6;
    const int lane = tid & 63;
    const int wM   = w & 1;
    const int wN   = w >> 1;
    const int rowBase   = blockIdx.x * 128;
    const int half      = blockIdx.y;
    const int codeBase0 = half * 4096;

    const int low3 = lane & 7, m15 = lane & 15, hi4 = lane >> 4;

    unsigned aOff[4];
#pragma unroll
    for (int i = 0; i < 4; ++i) {
        int cell = (w * 4 + i) * 64 + lane;
        int r = cell >> 3, qs = cell & 7, q = qs ^ (r & 7);
        aOff[i] = ((unsigned)(rowBase + r) * DIM + q * 8) * 2;
    }
    unsigned bOff[8];
#pragma unroll
    for (int i = 0; i < 8; ++i) {
        int cell = (w * 8 + i) * 64 + lane;
        int c = cell >> 3, qs = cell & 7, q = qs ^ (c & 7);
        bOff[i] = ((unsigned)c * DIM + q * 8) * 2;   // relative to code-tile base
    }

    int rIdx[4], cIdx[8];
#pragma unroll
    for (int mf = 0; mf < 4; ++mf) rIdx[mf] = (wM * 64 + mf * 16 + m15) * 8;
#pragma unroll
    for (int nf = 0; nf < 8; ++nf) cIdx[nf] = (wN * 128 + nf * 16 + m15) * 8;

    float g1v[4][4], g2v[4][4], g3v[4][4];
    unsigned nn[4][4];               // (n2<<16) | n1
#pragma unroll
    for (int mf = 0; mf < 4; ++mf)
#pragma unroll
        for (int rg = 0; rg < 4; ++rg) {
            g1v[mf][rg] = -3.4e38f; g2v[mf][rg] = -3.4e38f;
            g3v[mf][rg] = -3.4e38f; nn[mf][rg] = 0u;
        }

    const char* pA = (const char*)zh;
    for (int ct = 0; ct < 16; ++ct) {
        const int codeBase = codeBase0 + ct * 256;
        const char* pB = (const char*)ch + (size_t)codeBase * (DIM * 2);
        float4x acc[4][8];
#pragma unroll
        for (int mf = 0; mf < 4; ++mf)
#pragma unroll
            for (int nf = 0; nf < 8; ++nf) acc[mf][nf] = (float4x){0.f, 0.f, 0.f, 0.f};

        for (int dc = 0; dc < DIM; dc += 64) {
            const int dc2 = dc * 2;
            __syncthreads();
#pragma unroll
            for (int i = 0; i < 4; ++i)
                gl_lds16(pA + aOff[i] + dc2, &AsC[(w * 4 + i) * 64]);
#pragma unroll
            for (int i = 0; i < 8; ++i)
                gl_lds16(pB + bOff[i] + dc2, &BsC[(w * 8 + i) * 64]);
            __syncthreads();

#pragma unroll
            for (int ks = 0; ks < 2; ++ks) {
                const int qx = (ks * 4 + hi4) ^ low3;
                short8 a[4];
#pragma unroll
                for (int mf = 0; mf < 4; ++mf) a[mf] = AsC[rIdx[mf] + qx];
#pragma unroll
                for (int nf = 0; nf < 8; ++nf) {
                    short8 b = BsC[cIdx[nf] + qx];
#pragma unroll
                    for (int mf = 0; mf < 4; ++mf)
                        acc[mf][nf] = __builtin_amdgcn_mfma_f32_16x16x32_bf16(
                            a[mf], b, acc[mf][nf], 0, 0, 0);
                }
            }
        }

        // epilogue: running top-3 values / top-2 indices of g
#pragma unroll
        for (int nf = 0; nf < 8; ++nf) {
            int nb = codeBase + wN * 128 + nf * 16 + m15;
            float hv = hne2[nb];
#pragma unroll
            for (int mf = 0; mf < 4; ++mf) {
#pragma unroll
                for (int rg = 0; rg < 4; ++rg) {
                    float g = acc[mf][nf][rg] + hv;
                    bool t1 = g > g1v[mf][rg];
                    bool t2 = g > g2v[mf][rg];        // t1 implies t2
                    g3v[mf][rg] = t2 ? g2v[mf][rg] : fmaxf(g3v[mf][rg], g);
                    unsigned nup = t1 ? ((nn[mf][rg] << 16) | (unsigned)nb)
                                      : (((unsigned)nb << 16) | (nn[mf][rg] & 0xFFFFu));
                    nn[mf][rg]  = t2 ? nup : nn[mf][rg];
                    g2v[mf][rg] = t1 ? g1v[mf][rg] : (t2 ? g : g2v[mf][rg]);
                    g1v[mf][rg] = t1 ? g : g1v[mf][rg];
                }
            }
        }
    }

    // cross-lane top-3 merge over the 16 lanes sharing each row
#pragma unroll
    for (int mf = 0; mf < 4; ++mf)
#pragma unroll
        for (int rg = 0; rg < 4; ++rg) {
            float a1 = g1v[mf][rg], a2 = g2v[mf][rg], a3 = g3v[mf][rg];
            int an1 = (int)(nn[mf][rg] & 0xFFFFu);
            int an2 = (int)(nn[mf][rg] >> 16);
#pragma unroll
            for (int off = 1; off <= 8; off <<= 1) {
                float b1 = __shfl_xor(a1, off, 64);
                float b2 = __shfl_xor(a2, off, 64);
                float b3 = __shfl_xor(a3, off, 64);
                int  bn1 = __shfl_xor(an1, off, 64);
                int  bn2 = __shfl_xor(an2, off, 64);
                // insert (b1,bn1)
                if (b1 > a1 || (b1 == a1 && bn1 < an1)) {
                    a3 = a2; a2 = a1; an2 = an1; a1 = b1; an1 = bn1;
                } else if (b1 > a2 || (b1 == a2 && bn1 < an2)) {
                    a3 = a2; a2 = b1; an2 = bn1;
                } else a3 = fmaxf(a3, b1);
                // insert (b2,bn2)  (b2 <= b1, but handle generally)
                if (b2 > a1 || (b2 == a1 && bn2 < an1)) {
                    a3 = a2; a2 = a1; an2 = an1; a1 = b2; an1 = bn2;
                } else if (b2 > a2 || (b2 == a2 && bn2 < an2)) {
                    a3 = a2; a2 = b2; an2 = bn2;
                } else a3 = fmaxf(a3, b2);
                // b3 can never reach union top-2; only competes for 3rd
                a3 = fmaxf(a3, b3);
            }
            if (m15 == 0) {
                int row  = rowBase + wM * 64 + mf * 16 + hi4 * 4 + rg;
                int slot = half * 2 + wN;          // unique per (block.y, wave-col)
                pG [slot * N_VEC + row] = a1;
                pN [slot * N_VEC + row] = an1;
                pG2[slot * N_VEC + row] = a2;
                pN2[slot * N_VEC + row] = an2;
                pG3[slot * N_VEC + row] = a3;
            }
        }
}

// ---------------------------------------------------------------------------
// Kernel 3: merge 4 partial top-3 slots per row (exact global top-3).
//   g1-g3 <  MARGIN -> full rescue (all K, exact)      [rare, ~0.1%]
//   g1-g2 <  MARGIN <= g1-g3 -> pair rescue {n1,n2}    [~5%]
// Soundness: true best has g_bf16 >= g1 - MARGIN (bf16 err <= MARGIN/2).
// If g1-g3 >= MARGIN, exactly one code besides n1 can be in that range -> n2.
// Writes merged g1 back into pG slot 0 (own row only -> safe).
// ---------------------------------------------------------------------------
__global__ __launch_bounds__(256) void vq_scan(
    float* __restrict__ pG, const int* __restrict__ pN,
    const float* __restrict__ pG2, const int* __restrict__ pN2,
    const float* __restrict__ pG3,
    int* __restrict__ provIdx, int* __restrict__ flags,
    unsigned long long* __restrict__ keys,
    int* __restrict__ rescueRows, int* __restrict__ rescueCnt,
    int* __restrict__ pairRows, int* __restrict__ pairCnt,
    int* __restrict__ mergedN2) {
    int r = blockIdx.x * 256 + threadIdx.x;
    float g1 = pG[r], g2 = pG2[r], g3 = pG3[r];
    int   n1 = pN[r], n2 = pN2[r];
#pragma unroll
    for (int s = 1; s < 4; ++s) {
        float a1 = pG [s * N_VEC + r];
        int  an1 = pN [s * N_VEC + r];
        float a2 = pG2[s * N_VEC + r];
        int  an2 = pN2[s * N_VEC + r];
        float a3 = pG3[s * N_VEC + r];
        if (a1 > g1 || (a1 == g1 && an1 < n1)) {
            g3 = g2; g2 = g1; n2 = n1; g1 = a1; n1 = an1;
        } else if (a1 > g2 || (a1 == g2 && an1 < n2)) {
            g3 = g2; g2 = a1; n2 = an1;
        } else g3 = fmaxf(g3, a1);
        if (a2 > g1 || (a2 == g1 && an2 < n1)) {
            g3 = g2; g2 = g1; n2 = n1; g1 = a2; n1 = an2;
        } else if (a2 > g2 || (a2 == g2 && an2 < n2)) {
            g3 = g2; g2 = a2; n2 = an2;
        } else g3 = fmaxf(g3, a2);
        g3 = fmaxf(g3, a3);
    }
    provIdx[r] = n1;
    pG[r] = g1;                       // merged best (for loss)
    int fl = 0;
    if (g1 - g3 < MARGIN) {           // >=2 alternative candidates -> full scan
        fl = 1; keys[r] = ~0ull;
        int p = atomicAdd(rescueCnt, 1);
        rescueRows[p] = r;
    } else if (g1 - g2 < MARGIN) {    // exactly one alternative -> pair compare
        fl = 1; keys[r] = ~0ull;
        mergedN2[r] = n2;
        int p = atomicAdd(pairCnt, 1);
        pairRows[p] = r;
    }
    flags[r] = fl;
}

// ---------------------------------------------------------------------------
// Kernel 3b: pair rescue. One wave per flagged row: exact fp32 kv = e2/2 - x.e
// for codes n1, n2; pick min (lowest index on tie); direct-store packed key.
// Pair rows and full-rescue rows are disjoint -> no atomics needed.
// ---------------------------------------------------------------------------
__global__ __launch_bounds__(256) void vq_pair(
    const float* __restrict__ z, const float* __restrict__ cb,
    const float* __restrict__ hne2,
    const int* __restrict__ provIdx, const int* __restrict__ mergedN2,
    const int* __restrict__ pairRows, const int* __restrict__ pairCnt,
    unsigned long long* __restrict__ keys) {
    const int lane = threadIdx.x & 63;
    const int wid  = blockIdx.x * 4 + (threadIdx.x >> 6);
    const int nW   = gridDim.x * 4;
    const int cnt  = *pairCnt;
    for (int i = wid; i < cnt; i += nW) {
        int r  = pairRows[i];
        int n1 = provIdx[r];
        int n2 = mergedN2[r];
        const float4* xz = (const float4*)(z  + (size_t)r  * DIM);
        const float4* c1 = (const float4*)(cb + (size_t)n1 * DIM);
        const float4* c2 = (const float4*)(cb + (size_t)n2 * DIM);
        float4 x0 = xz[lane * 2], x1 = xz[lane * 2 + 1];
        float4 a0 = c1[lane * 2], a1 = c1[lane * 2 + 1];
        float4 b0 = c2[lane * 2], b1 = c2[lane * 2 + 1];
        float d1 = x0.x*a0.x + x0.y*a0.y + x0.z*a0.z + x0.w*a0.w
                 + x1.x*a1.x + x1.y*a1.y + x1.z*a1.z + x1.w*a1.w;
        float d2 = x0.x*b0.x + x0.y*b0.y + x0.z*b0.z + x0.w*b0.w
                 + x1.x*b1.x + x1.y*b1.y + x1.z*b1.z + x1.w*b1.w;
#pragma unroll
        for (int off = 32; off >= 1; off >>= 1) {
            d1 += __shfl_xor(d1, off, 64);
            d2 += __shfl_xor(d2, off, 64);
        }
        if (lane == 0) {
            float kv1 = -hne2[n1] - d1;
            float kv2 = -hne2[n2] - d2;
            int nsel; float kv;
            if (kv2 < kv1 || (kv2 == kv1 && n2 < n1)) { kv = kv2; nsel = n2; }
            else                                      { kv = kv1; nsel = n1; }
            keys[r] = ((unsigned long long)__float_as_uint(kv) << 32) |
                      (unsigned long long)(unsigned)nsel;
        }
    }
}

// ---------------------------------------------------------------------------
// Kernel 4: exact fp32 rescue over ALL codes, ROW-major over compacted
// full-rescue slots (now rare: only rows with g1-g3 < MARGIN).
// ---------------------------------------------------------------------------
#define RBM 64
#define RBK 256
#define RBD 32

__global__ __launch_bounds__(256, 2) void vq_rescue(
    const float* __restrict__ z, const float* __restrict__ cb,
    const float* __restrict__ hne2,
    const int* __restrict__ rescueRows, const int* __restrict__ rescueCnt,
    unsigned long long* __restrict__ keys) {
    __shared__ float As[RBD][RBM];   // 8 KB, transposed
    __shared__ float Bs[RBD][RBK];   // 32 KB, transposed
    __shared__ int   rowOf[RBM];

    const int tid = threadIdx.x;
    const int tx  = tid & 31;
    const int ty  = tid >> 5;
    const int cnt = *rescueCnt;
    const int codeBase0 = blockIdx.y * 512;      // grid.y = 16
    const int sw = (tx & 8) ? 4 : 0;
    const int sRow = tid >> 2;
    const int sQ   = tid & 3;

    for (int rt = blockIdx.x; rt * RBM < cnt; rt += gridDim.x) {
        const int slotBase = rt * RBM;
        __syncthreads();   // prior iteration fully done before rowOf/tiles change
        if (tid < RBM) rowOf[tid] = rescueRows[slotBase + tid];
        __syncthreads();

        float best[8];
        int   bidx[8];
#pragma unroll
        for (int i = 0; i < 8; ++i) { best[i] = 3.4e38f; bidx[i] = K_CODES; }

        for (int kt = 0; kt < 2; ++kt) {
            const int codeBase = codeBase0 + kt * RBK;
            float acc[8][8];
#pragma unroll
            for (int i = 0; i < 8; ++i)
#pragma unroll
                for (int j = 0; j < 8; ++j) acc[i][j] = 0.0f;

            for (int dc = 0; dc < DIM; dc += RBD) {
                __syncthreads();
                {   // stage A (indirected rows)
                    const float* srcA = z + (size_t)rowOf[sRow] * DIM + dc + sQ * 8;
                    float4 va0 = ((const float4*)srcA)[0];
                    float4 va1 = ((const float4*)srcA)[1];
                    int c0 = sQ * 8;
                    As[c0 + 0][sRow] = va0.x; As[c0 + 1][sRow] = va0.y;
                    As[c0 + 2][sRow] = va0.z; As[c0 + 3][sRow] = va0.w;
                    As[c0 + 4][sRow] = va1.x; As[c0 + 5][sRow] = va1.y;
                    As[c0 + 6][sRow] = va1.z; As[c0 + 7][sRow] = va1.w;
                }
                {   // stage B
                    const float4* srcB = (const float4*)(cb + (size_t)(codeBase + tid) * DIM + dc);
#pragma unroll
                    for (int j = 0; j < 8; ++j) {
                        float4 v = srcB[j];
                        Bs[j * 4 + 0][tid] = v.x; Bs[j * 4 + 1][tid] = v.y;
                        Bs[j * 4 + 2][tid] = v.z; Bs[j * 4 + 3][tid] = v.w;
                    }
                }
                __syncthreads();

#pragma unroll
                for (int d = 0; d < RBD; ++d) {
                    float a[8], b[8];
                    *(float4*)&a[0] = *(const float4*)&As[d][ty * 8];
                    *(float4*)&a[4] = *(const float4*)&As[d][ty * 8 + 4];
                    *(float4*)&b[0] = *(const float4*)&Bs[d][tx * 8 + sw];
                    *(float4*)&b[4] = *(const float4*)&Bs[d][tx * 8 + (sw ^ 4)];
#pragma unroll
                    for (int i = 0; i < 8; ++i)
#pragma unroll
                        for (int j = 0; j < 8; ++j) acc[i][j] += a[i] * b[j];
                }
            }

#pragma unroll
            for (int j = 0; j < 8; ++j) {
                int code = codeBase + tx * 8 + ((j < 4) ? (sw + j) : ((sw ^ 4) + j - 4));
                float ev = -hne2[code];           // = e2/2
#pragma unroll
                for (int i = 0; i < 8; ++i) {
                    float kv = ev - acc[i][j];    // = e2/2 - x.e  (> 0)
                    if (kv < best[i] || (kv == best[i] && code < bidx[i])) {
                        best[i] = kv;
                        bidx[i] = code;
                    }
                }
            }
        }

        // reduce argmin across the 32 tx-lanes sharing each row group
#pragma unroll
        for (int off = 16; off >= 1; off >>= 1) {
#pragma unroll
            for (int i = 0; i < 8; ++i) {
                float od = __shfl_xor(best[i], off, 64);
                int   oi = __shfl_xor(bidx[i], off, 64);
                if (od < best[i] || (od == best[i] && oi < bidx[i])) {
                    best[i] = od;
                    bidx[i] = oi;
                }
            }
        }

        if (tx == 0) {
#pragma unroll
            for (int i = 0; i < 8; ++i) {
                int slot = slotBase + ty * 8 + i;
                if (slot < cnt) {
                    unsigned long long key =
                        ((unsigned long long)__float_as_uint(best[i]) << 32) |
                        (unsigned long long)(unsigned)bidx[i];
                    atomicMin(&keys[rowOf[ty * 8 + i]], key);
                }
            }
        }
    }
}

// ---------------------------------------------------------------------------
// Kernel 5: final per-row results: index, counts, loss partial, z_q gather.
// ---------------------------------------------------------------------------
__global__ __launch_bounds__(256) void vq_final(
    const float* __restrict__ gBest, const int* __restrict__ provIdx,
    const int* __restrict__ flags, const unsigned long long* __restrict__ keys,
    const float* __restrict__ x2, const float* __restrict__ cb,
    float* __restrict__ zq, float* __restrict__ idxf,
    float* __restrict__ counts, float* __restrict__ lossAcc) {
    __shared__ int   sIdx[256];
    __shared__ float wsum[4];
    const int tid = threadIdx.x;
    const int r   = blockIdx.x * 256 + tid;

    int n; float dist;
    if (flags[r]) {
        unsigned long long k = keys[r];
        n = (int)(unsigned)(k & 0xffffffffu);
        float kv = __uint_as_float((unsigned)(k >> 32));
        dist = x2[r] + 2.0f * kv;          // x2 + e2 - 2 x.e
    } else {
        n = provIdx[r];
        dist = x2[r] - 2.0f * gBest[r];
    }
    sIdx[tid] = n;
    idxf[r]   = (float)n;
    atomicAdd(&counts[n], 1.0f);

    float ls = dist;
#pragma unroll
    for (int off = 32; off >= 1; off >>= 1) ls += __shfl_xor(ls, off, 64);
    if ((tid & 63) == 0) wsum[tid >> 6] = ls;
    __syncthreads();
    if (tid == 0) atomicAdd(lossAcc, wsum[0] + wsum[1] + wsum[2] + wsum[3]);

    const float4* cb4 = (const float4*)cb;
    float4* zq4 = (float4*)(zq + (size_t)blockIdx.x * 256 * DIM);
    for (int t = tid; t < 256 * (DIM / 4); t += 256) {
        int row = t >> 7, f4 = t & 127;
        zq4[(size_t)row * 128 + f4] = cb4[(size_t)sIdx[row] * 128 + f4];
    }
}

// ---------------------------------------------------------------------------
// Kernel 6: finalize scalars
// ---------------------------------------------------------------------------
__global__ __launch_bounds__(256) void vq_finalize(const float* __restrict__ counts,
                                                   const float* __restrict__ lossAcc,
                                                   float* __restrict__ out_loss,
                                                   float* __restrict__ out_perp) {
    __shared__ float wsum[4];
    int tid = threadIdx.x;
    float s = 0.0f;
    for (int i = tid; i < K_CODES; i += 256) {
        float p = counts[i] * (1.0f / (float)N_VEC);
        s += p * logf(p + 1e-10f);
    }
#pragma unroll
    for (int off = 32; off >= 1; off >>= 1) s += __shfl_xor(s, off, 64);
    if ((tid & 63) == 0) wsum[tid >> 6] = s;
    __syncthreads();
    if (tid == 0) {
        *out_perp = expf(-(wsum[0] + wsum[1] + wsum[2] + wsum[3]));
        *out_loss = 1.25f * lossAcc[0] / (float)(N_VEC * DIM);
    }
}

// ---------------------------------------------------------------------------
// ws layout (bytes), total ~44.6 MB (unchanged):
//   x2 @0 131072 | hne2 @131072 32768 | counts @163840 32768 | lossAcc @196608 4
//   rescueCnt @196612 4 | pairCnt @196616 4 | provIdx @262144 131072
//   flags @393216 131072 | keys @524288 262144 | rescueRows @786432 131072
//   pG @1048576 524288 | pN @1572864 524288 | pG2 @2097152 524288
//   zh @2621440 33554432 | ch @36175872 8388608
// Scratch in d_out's zq region (consumed by scan/pair BEFORE vq_final
// overwrites zq; stream-ordered, safe):
//   pN2 @out+0 524288 | pG3 @out+524288 524288
//   mergedN2 @out+1048576 131072 | pairRows @out+1179648 131072
// ---------------------------------------------------------------------------
extern "C" void kernel_launch(void* const* d_in, const int* in_sizes, int n_in,
                              void* d_out, int out_size, void* d_ws, size_t ws_size,
                              hipStream_t stream) {
    (void)in_sizes; (void)n_in; (void)out_size; (void)ws_size;
    const float* z  = (const float*)d_in[0];
    const float* cb = (const float*)d_in[1];

    char* ws = (char*)d_ws;
    float* x2        = (float*)(ws + 0);
    float* hne2      = (float*)(ws + 131072);
    float* counts    = (float*)(ws + 163840);
    float* lossAcc   = (float*)(ws + 196608);
    int*   rescueCnt = (int*)  (ws + 196612);
    int*   pairCnt   = (int*)  (ws + 196616);
    int*   provIdx   = (int*)  (ws + 262144);
    int*   flags     = (int*)  (ws + 393216);
    unsigned long long* keys = (unsigned long long*)(ws + 524288);
    int*   rescueRows = (int*) (ws + 786432);
    float* pG        = (float*)(ws + 1048576);
    int*   pN        = (int*)  (ws + 1572864);
    float* pG2       = (float*)(ws + 2097152);
    unsigned short* zh = (unsigned short*)(ws + 2621440);
    unsigned short* ch = (unsigned short*)(ws + 36175872);

    float* out      = (float*)d_out;
    float* zq       = out;
    float* out_loss = out + 16777216;
    float* idxf     = out + 16777217;
    float* out_perp = out + 16777217 + 32768;

    // scratch inside zq region (dead before vq_final writes zq)
    char* sc = (char*)d_out;
    int*   pN2      = (int*)  (sc + 0);
    float* pG3      = (float*)(sc + 524288);
    int*   mergedN2 = (int*)  (sc + 1048576);
    int*   pairRows = (int*)  (sc + 1179648);

    // zero counts + lossAcc + rescueCnt + pairCnt (contiguous) and rescueRows
    hipMemsetAsync(counts, 0, 32768 + 16, stream);
    hipMemsetAsync(rescueRows, 0, 131072, stream);
    vq_prep<<<(N_VEC + K_CODES) / 4, 256, 0, stream>>>(z, cb, x2, hne2, zh, ch);
    dim3 grid(N_VEC / 128, 2);
    vq_gemm<<<grid, 256, 0, stream>>>(zh, ch, hne2, pG, pN, pG2, pN2, pG3);
    vq_scan<<<N_VEC / 256, 256, 0, stream>>>(pG, pN, pG2, pN2, pG3, provIdx, flags,
                                             keys, rescueRows, rescueCnt,
                                             pairRows, pairCnt, mergedN2);
    vq_pair<<<128, 256, 0, stream>>>(z, cb, hne2, provIdx, mergedN2,
                                     pairRows, pairCnt, keys);
    dim3 rgrid(64, 16);
    vq_rescue<<<rgrid, 256, 0, stream>>>(z, cb, hne2, rescueRows, rescueCnt, keys);
    vq_final<<<N_VEC / 256, 256, 0, stream>>>(pG, provIdx, flags, keys, x2, cb,
                                              zq, idxf, counts, lossAcc);
    vq_finalize<<<1, 256, 0, stream>>>(counts, lossAcc, out_loss, out_perp);
}

// Round 3
// 716.426 us; speedup vs baseline: 1.0306x; 1.0306x over previous
//
#include <hip/hip_runtime.h>
#include <hip/hip_bf16.h>

#define K_CODES 8192
#define DIM     512
#define N_VEC   32768
// flag threshold on g = x.e - e2/2 : bf16-dot error budget (~0.35) plus
// packed-tag quantization (<=0.125 for |g|<1024). Near-ties are rescued
// exactly, so MARGIN only affects rescue counts, not correctness.
#define MARGIN  0.5f

typedef __attribute__((ext_vector_type(8))) short   short8;   // bf16x8 MFMA operand
typedef __attribute__((ext_vector_type(8))) unsigned short ushort8;
typedef __attribute__((ext_vector_type(4))) float   float4x;  // MFMA C/D frag

// async global->LDS, 16 B/lane. LDS dest = wave-uniform base + lane*16.
__device__ inline void gl_lds16(const void* g, void* l) {
    __builtin_amdgcn_global_load_lds(
        (const __attribute__((address_space(1))) unsigned int*)g,
        (__attribute__((address_space(3))) unsigned int*)l, 16, 0, 0);
}

// fp32 -> bf16 bits, round-to-nearest-even
__device__ inline unsigned short f2bf(float f) {
    unsigned int u = __float_as_uint(f);
    return (unsigned short)((u + 0x7FFFu + ((u >> 16) & 1u)) >> 16);
}

__device__ inline float med3(float a, float b, float c) {
    return __builtin_amdgcn_fmed3f(a, b, c);
}

// ---------------------------------------------------------------------------
// Kernel 1: prep. rows [0,N_VEC) from z -> zh + x2 ; rows [N_VEC,+K) from cb
// -> ch + hne2 = -0.5*||e||^2.  One wave per row.
// ---------------------------------------------------------------------------
__global__ __launch_bounds__(256) void vq_prep(
    const float* __restrict__ z, const float* __restrict__ cb,
    float* __restrict__ x2, float* __restrict__ hne2,
    unsigned short* __restrict__ zh, unsigned short* __restrict__ ch) {
    int wave = threadIdx.x >> 6;
    int lane = threadIdx.x & 63;
    int row  = blockIdx.x * 4 + wave;
    bool isZ = row < N_VEC;
    int lr = isZ ? row : row - N_VEC;
    const float* src = isZ ? z + (size_t)row * DIM : cb + (size_t)lr * DIM;

    const float4* s4 = (const float4*)src;
    float4 v0 = s4[lane * 2];
    float4 v1 = s4[lane * 2 + 1];
    float f[8] = {v0.x, v0.y, v0.z, v0.w, v1.x, v1.y, v1.z, v1.w};

    float s = 0.0f;
    ushort8 h8;
#pragma unroll
    for (int i = 0; i < 8; ++i) { s += f[i] * f[i]; h8[i] = f2bf(f[i]); }
    ((ushort8*)(isZ ? zh : ch))[(size_t)lr * 64 + lane] = h8;

#pragma unroll
    for (int off = 32; off >= 1; off >>= 1) s += __shfl_xor(s, off, 64);
    if (lane == 0) {
        if (isZ) x2[lr] = s;
        else     hne2[lr] = -0.5f * s;
    }
}

// ---------------------------------------------------------------------------
// Kernel 2: bf16 MFMA GEMM + fused top-3 of g = x.e - e2/2 via PACKED floats:
// the candidate's in-slot identity (ct:4 | nf:3 | m15:4 = 11 bits) replaces
// the low 11 mantissa bits of g. Running top-3 is then pure float med3/max
// (5-6 VALU/candidate, no index registers). Quantization <= 2^(exp-12)
// (<=0.125 for |g|<1024) is absorbed by MARGIN; in-quantum ties order by tag,
// which for negative g prefers LOWER code; any such tie is within MARGIN ->
// flagged -> resolved exactly downstream.
// Block = 128 rows x 4096 codes (half=blockIdx.y), 16 tiles of 256 codes.
// 4 waves in 2x2 (wM x wN); per-wave 64x128 tile.
// Partials written RACE-FREE to slot = half*2 + wN (4 slots per row).
// ---------------------------------------------------------------------------
__global__ __launch_bounds__(256, 2) void vq_gemm(
    const unsigned short* __restrict__ zh, const unsigned short* __restrict__ ch,
    const float* __restrict__ hne2,
    float* __restrict__ pG, int* __restrict__ pN, float* __restrict__ pG2,
    int* __restrict__ pN2, float* __restrict__ pG3) {
    __shared__ short8 AsC[1024];   // 128 rows x 8 octet-cells, XOR-swizzled (16 KB)
    __shared__ short8 BsC[2048];   // 256 codes x 8 octet-cells, XOR-swizzled (32 KB)

    const int tid  = threadIdx.x;
    const int w    = tid >> 6;
    const int lane = tid & 63;
    const int wM   = w & 1;
    const int wN   = w >> 1;
    const int rowBase   = blockIdx.x * 128;
    const int half      = blockIdx.y;
    const int codeBase0 = half * 4096;

    const int low3 = lane & 7, m15 = lane & 15, hi4 = lane >> 4;

    unsigned aOff[4];
#pragma unroll
    for (int i = 0; i < 4; ++i) {
        int cell = (w * 4 + i) * 64 + lane;
        int r = cell >> 3, qs = cell & 7, q = qs ^ (r & 7);
        aOff[i] = ((unsigned)(rowBase + r) * DIM + q * 8) * 2;
    }
    unsigned bOff[8];
#pragma unroll
    for (int i = 0; i < 8; ++i) {
        int cell = (w * 8 + i) * 64 + lane;
        int c = cell >> 3, qs = cell & 7, q = qs ^ (c & 7);
        bOff[i] = ((unsigned)c * DIM + q * 8) * 2;   // relative to code-tile base
    }

    int rIdx[4], cIdx[8];
#pragma unroll
    for (int mf = 0; mf < 4; ++mf) rIdx[mf] = (wM * 64 + mf * 16 + m15) * 8;
#pragma unroll
    for (int nf = 0; nf < 8; ++nf) cIdx[nf] = (wN * 128 + nf * 16 + m15) * 8;

    float g1v[4][4], g2v[4][4], g3v[4][4];
#pragma unroll
    for (int mf = 0; mf < 4; ++mf)
#pragma unroll
        for (int rg = 0; rg < 4; ++rg) {
            g1v[mf][rg] = -3.4e38f; g2v[mf][rg] = -3.4e38f; g3v[mf][rg] = -3.4e38f;
        }

    const char* pA = (const char*)zh;
    for (int ct = 0; ct < 16; ++ct) {
        const int codeBase = codeBase0 + ct * 256;
        const char* pB = (const char*)ch + (size_t)codeBase * (DIM * 2);
        float4x acc[4][8];
#pragma unroll
        for (int mf = 0; mf < 4; ++mf)
#pragma unroll
            for (int nf = 0; nf < 8; ++nf) acc[mf][nf] = (float4x){0.f, 0.f, 0.f, 0.f};

        for (int dc = 0; dc < DIM; dc += 64) {
            const int dc2 = dc * 2;
            __syncthreads();
#pragma unroll
            for (int i = 0; i < 4; ++i)
                gl_lds16(pA + aOff[i] + dc2, &AsC[(w * 4 + i) * 64]);
#pragma unroll
            for (int i = 0; i < 8; ++i)
                gl_lds16(pB + bOff[i] + dc2, &BsC[(w * 8 + i) * 64]);
            __syncthreads();

#pragma unroll
            for (int ks = 0; ks < 2; ++ks) {
                const int qx = (ks * 4 + hi4) ^ low3;
                short8 a[4];
#pragma unroll
                for (int mf = 0; mf < 4; ++mf) a[mf] = AsC[rIdx[mf] + qx];
#pragma unroll
                for (int nf = 0; nf < 8; ++nf) {
                    short8 b = BsC[cIdx[nf] + qx];
#pragma unroll
                    for (int mf = 0; mf < 4; ++mf)
                        acc[mf][nf] = __builtin_amdgcn_mfma_f32_16x16x32_bf16(
                            a[mf], b, acc[mf][nf], 0, 0, 0);
                }
            }
        }

        // epilogue: packed running top-3 (5-6 VALU per candidate)
#pragma unroll
        for (int nf = 0; nf < 8; ++nf) {
            int nb = codeBase + wN * 128 + nf * 16 + m15;
            float hv = hne2[nb];
            unsigned tag = ((unsigned)ct << 7) | ((unsigned)nf << 4) | (unsigned)m15;
#pragma unroll
            for (int mf = 0; mf < 4; ++mf) {
#pragma unroll
                for (int rg = 0; rg < 4; ++rg) {
                    float g  = acc[mf][nf][rg] + hv;
                    float pk = __uint_as_float(
                        (__float_as_uint(g) & 0xFFFFF800u) | tag);
                    g3v[mf][rg] = med3(pk, g2v[mf][rg], g3v[mf][rg]);
                    g2v[mf][rg] = med3(pk, g1v[mf][rg], g2v[mf][rg]);
                    g1v[mf][rg] = fmaxf(g1v[mf][rg], pk);
                }
            }
        }
    }

    // cross-lane top-3 merge over the 16 lanes sharing each row (packed floats
    // carry identity; sequential insert of b1,b2,b3 is exact for top-3)
#pragma unroll
    for (int mf = 0; mf < 4; ++mf)
#pragma unroll
        for (int rg = 0; rg < 4; ++rg) {
            float a1 = g1v[mf][rg], a2 = g2v[mf][rg], a3 = g3v[mf][rg];
#pragma unroll
            for (int off = 1; off <= 8; off <<= 1) {
                float b1 = __shfl_xor(a1, off, 64);
                float b2 = __shfl_xor(a2, off, 64);
                float b3 = __shfl_xor(a3, off, 64);
                a3 = med3(b1, a2, a3);
                a2 = med3(b1, a1, a2);
                a1 = fmaxf(a1, b1);
                a3 = med3(b2, a2, a3);   // b2 <= b1 <= a1: rank-1 unaffected
                a2 = med3(b2, a1, a2);
                a3 = med3(b3, a2, a3);   // b3 only competes for rank 3
            }
            if (m15 == 0) {
                unsigned u1 = __float_as_uint(a1);
                unsigned u2 = __float_as_uint(a2);
                unsigned u3 = __float_as_uint(a3);
                int t1 = (int)(u1 & 0x7FFu), t2 = (int)(u2 & 0x7FFu);
                int c1 = codeBase0 + ((t1 & 0x780) << 1) + wN * 128 + (t1 & 0x7F);
                int c2 = codeBase0 + ((t2 & 0x780) << 1) + wN * 128 + (t2 & 0x7F);
                int row  = rowBase + wM * 64 + mf * 16 + hi4 * 4 + rg;
                int slot = half * 2 + wN;          // unique per (block.y, wave-col)
                pG [slot * N_VEC + row] = __uint_as_float(u1 & 0xFFFFF800u);
                pN [slot * N_VEC + row] = c1;
                pG2[slot * N_VEC + row] = __uint_as_float(u2 & 0xFFFFF800u);
                pN2[slot * N_VEC + row] = c2;
                pG3[slot * N_VEC + row] = __uint_as_float(u3 & 0xFFFFF800u);
            }
        }
}

// ---------------------------------------------------------------------------
// Kernel 3: merge 4 partial top-3 slots per row (exact global top-3).
//   g1-g3 <  MARGIN -> full rescue (all K, exact)      [rare, ~0.5%]
//   g1-g2 <  MARGIN <= g1-g3 -> pair rescue {n1,n2}    [~7%]
// Soundness: true best has screened-g >= g1 - MARGIN (bf16 err + quantization
// <= MARGIN). If g1-g3 >= MARGIN, exactly one code besides n1 can be in that
// range -> n2.  Writes merged g1 back into pG slot 0 (own row only -> safe).
// ---------------------------------------------------------------------------
__global__ __launch_bounds__(256) void vq_scan(
    float* __restrict__ pG, const int* __restrict__ pN,
    const float* __restrict__ pG2, const int* __restrict__ pN2,
    const float* __restrict__ pG3,
    int* __restrict__ provIdx, int* __restrict__ flags,
    unsigned long long* __restrict__ keys,
    int* __restrict__ rescueRows, int* __restrict__ rescueCnt,
    int* __restrict__ pairRows, int* __restrict__ pairCnt,
    int* __restrict__ mergedN2) {
    int r = blockIdx.x * 256 + threadIdx.x;
    float g1 = pG[r], g2 = pG2[r], g3 = pG3[r];
    int   n1 = pN[r], n2 = pN2[r];
#pragma unroll
    for (int s = 1; s < 4; ++s) {
        float a1 = pG [s * N_VEC + r];
        int  an1 = pN [s * N_VEC + r];
        float a2 = pG2[s * N_VEC + r];
        int  an2 = pN2[s * N_VEC + r];
        float a3 = pG3[s * N_VEC + r];
        if (a1 > g1 || (a1 == g1 && an1 < n1)) {
            g3 = g2; g2 = g1; n2 = n1; g1 = a1; n1 = an1;
        } else if (a1 > g2 || (a1 == g2 && an1 < n2)) {
            g3 = g2; g2 = a1; n2 = an1;
        } else g3 = fmaxf(g3, a1);
        if (a2 > g1 || (a2 == g1 && an2 < n1)) {
            g3 = g2; g2 = g1; n2 = n1; g1 = a2; n1 = an2;
        } else if (a2 > g2 || (a2 == g2 && an2 < n2)) {
            g3 = g2; g2 = a2; n2 = an2;
        } else g3 = fmaxf(g3, a2);
        g3 = fmaxf(g3, a3);
    }
    provIdx[r] = n1;
    pG[r] = g1;                       // merged best (for loss)
    int fl = 0;
    if (g1 - g3 < MARGIN) {           // >=2 alternative candidates -> full scan
        fl = 1; keys[r] = ~0ull;
        int p = atomicAdd(rescueCnt, 1);
        rescueRows[p] = r;
    } else if (g1 - g2 < MARGIN) {    // exactly one alternative -> pair compare
        fl = 1; keys[r] = ~0ull;
        mergedN2[r] = n2;
        int p = atomicAdd(pairCnt, 1);
        pairRows[p] = r;
    }
    flags[r] = fl;
}

// ---------------------------------------------------------------------------
// Kernel 3b: pair rescue. One wave per flagged row: exact fp32 kv = e2/2 - x.e
// for codes n1, n2; pick min (lowest index on tie); direct-store packed key.
// Pair rows and full-rescue rows are disjoint -> no atomics needed.
// ---------------------------------------------------------------------------
__global__ __launch_bounds__(256) void vq_pair(
    const float* __restrict__ z, const float* __restrict__ cb,
    const float* __restrict__ hne2,
    const int* __restrict__ provIdx, const int* __restrict__ mergedN2,
    const int* __restrict__ pairRows, const int* __restrict__ pairCnt,
    unsigned long long* __restrict__ keys) {
    const int lane = threadIdx.x & 63;
    const int wid  = blockIdx.x * 4 + (threadIdx.x >> 6);
    const int nW   = gridDim.x * 4;
    const int cnt  = *pairCnt;
    for (int i = wid; i < cnt; i += nW) {
        int r  = pairRows[i];
        int n1 = provIdx[r];
        int n2 = mergedN2[r];
        const float4* xz = (const float4*)(z  + (size_t)r  * DIM);
        const float4* c1 = (const float4*)(cb + (size_t)n1 * DIM);
        const float4* c2 = (const float4*)(cb + (size_t)n2 * DIM);
        float4 x0 = xz[lane * 2], x1 = xz[lane * 2 + 1];
        float4 a0 = c1[lane * 2], a1 = c1[lane * 2 + 1];
        float4 b0 = c2[lane * 2], b1 = c2[lane * 2 + 1];
        float d1 = x0.x*a0.x + x0.y*a0.y + x0.z*a0.z + x0.w*a0.w
                 + x1.x*a1.x + x1.y*a1.y + x1.z*a1.z + x1.w*a1.w;
        float d2 = x0.x*b0.x + x0.y*b0.y + x0.z*b0.z + x0.w*b0.w
                 + x1.x*b1.x + x1.y*b1.y + x1.z*b1.z + x1.w*b1.w;
#pragma unroll
        for (int off = 32; off >= 1; off >>= 1) {
            d1 += __shfl_xor(d1, off, 64);
            d2 += __shfl_xor(d2, off, 64);
        }
        if (lane == 0) {
            float kv1 = -hne2[n1] - d1;
            float kv2 = -hne2[n2] - d2;
            int nsel; float kv;
            if (kv2 < kv1 || (kv2 == kv1 && n2 < n1)) { kv = kv2; nsel = n2; }
            else                                      { kv = kv1; nsel = n1; }
            keys[r] = ((unsigned long long)__float_as_uint(kv) << 32) |
                      (unsigned long long)(unsigned)nsel;
        }
    }
}

// ---------------------------------------------------------------------------
// Kernel 4: exact fp32 rescue over ALL codes for rows with g1-g3 < MARGIN.
// grid (32, 32): y = 256-code chunk (half the old serial depth), x = row
// tiles (grid-stride). Thread's 8 codes are tx + 32*j -> B reads are
// lane-consecutive (conflict-free; old tx*8+j layout was 8-way conflicted).
// ---------------------------------------------------------------------------
#define RBM 64
#define RBK 256
#define RBD 32

__global__ __launch_bounds__(256, 2) void vq_rescue(
    const float* __restrict__ z, const float* __restrict__ cb,
    const float* __restrict__ hne2,
    const int* __restrict__ rescueRows, const int* __restrict__ rescueCnt,
    unsigned long long* __restrict__ keys) {
    __shared__ float As[RBD][RBM];   // 8 KB, transposed
    __shared__ float Bs[RBD][RBK];   // 32 KB, transposed
    __shared__ int   rowOf[RBM];

    const int tid = threadIdx.x;
    const int tx  = tid & 31;
    const int ty  = tid >> 5;
    const int cnt = *rescueCnt;
    const int codeBase = blockIdx.y * RBK;       // grid.y = 32
    const int sRow = tid >> 2;
    const int sQ   = tid & 3;

    for (int rt = blockIdx.x; rt * RBM < cnt; rt += gridDim.x) {
        const int slotBase = rt * RBM;
        __syncthreads();   // prior iteration fully done before rowOf/tiles change
        if (tid < RBM) rowOf[tid] = rescueRows[slotBase + tid];
        __syncthreads();

        float acc[8][8];
#pragma unroll
        for (int i = 0; i < 8; ++i)
#pragma unroll
            for (int j = 0; j < 8; ++j) acc[i][j] = 0.0f;

        for (int dc = 0; dc < DIM; dc += RBD) {
            __syncthreads();
            {   // stage A (indirected rows)
                const float* srcA = z + (size_t)rowOf[sRow] * DIM + dc + sQ * 8;
                float4 va0 = ((const float4*)srcA)[0];
                float4 va1 = ((const float4*)srcA)[1];
                int c0 = sQ * 8;
                As[c0 + 0][sRow] = va0.x; As[c0 + 1][sRow] = va0.y;
                As[c0 + 2][sRow] = va0.z; As[c0 + 3][sRow] = va0.w;
                As[c0 + 4][sRow] = va1.x; As[c0 + 5][sRow] = va1.y;
                As[c0 + 6][sRow] = va1.z; As[c0 + 7][sRow] = va1.w;
            }
            {   // stage B: one code per thread
                const float4* srcB = (const float4*)(cb + (size_t)(codeBase + tid) * DIM + dc);
#pragma unroll
                for (int j = 0; j < 8; ++j) {
                    float4 v = srcB[j];
                    Bs[j * 4 + 0][tid] = v.x; Bs[j * 4 + 1][tid] = v.y;
                    Bs[j * 4 + 2][tid] = v.z; Bs[j * 4 + 3][tid] = v.w;
                }
            }
            __syncthreads();

#pragma unroll
            for (int d = 0; d < RBD; ++d) {
                float a[8], b[8];
                *(float4*)&a[0] = *(const float4*)&As[d][ty * 8];
                *(float4*)&a[4] = *(const float4*)&As[d][ty * 8 + 4];
#pragma unroll
                for (int j = 0; j < 8; ++j) b[j] = Bs[d][tx + 32 * j];
#pragma unroll
                for (int i = 0; i < 8; ++i)
#pragma unroll
                    for (int j = 0; j < 8; ++j) acc[i][j] += a[i] * b[j];
            }
        }

        float best[8];
        int   bidx[8];
#pragma unroll
        for (int i = 0; i < 8; ++i) { best[i] = 3.4e38f; bidx[i] = K_CODES; }

#pragma unroll
        for (int j = 0; j < 8; ++j) {
            int code = codeBase + tx + 32 * j;
            float ev = -hne2[code];               // = e2/2
#pragma unroll
            for (int i = 0; i < 8; ++i) {
                float kv = ev - acc[i][j];        // = e2/2 - x.e  (> 0)
                if (kv < best[i] || (kv == best[i] && code < bidx[i])) {
                    best[i] = kv;
                    bidx[i] = code;
                }
            }
        }

        // reduce argmin across the 32 tx-lanes sharing each row group
#pragma unroll
        for (int off = 16; off >= 1; off >>= 1) {
#pragma unroll
            for (int i = 0; i < 8; ++i) {
                float od = __shfl_xor(best[i], off, 64);
                int   oi = __shfl_xor(bidx[i], off, 64);
                if (od < best[i] || (od == best[i] && oi < bidx[i])) {
                    best[i] = od;
                    bidx[i] = oi;
                }
            }
        }

        if (tx == 0) {
#pragma unroll
            for (int i = 0; i < 8; ++i) {
                int slot = slotBase + ty * 8 + i;
                if (slot < cnt) {
                    unsigned long long key =
                        ((unsigned long long)__float_as_uint(best[i]) << 32) |
                        (unsigned long long)(unsigned)bidx[i];
                    atomicMin(&keys[rowOf[ty * 8 + i]], key);
                }
            }
        }
    }
}

// ---------------------------------------------------------------------------
// Kernel 5: final per-row results: index, counts, loss partial, z_q gather.
// ---------------------------------------------------------------------------
__global__ __launch_bounds__(256) void vq_final(
    const float* __restrict__ gBest, const int* __restrict__ provIdx,
    const int* __restrict__ flags, const unsigned long long* __restrict__ keys,
    const float* __restrict__ x2, const float* __restrict__ cb,
    float* __restrict__ zq, float* __restrict__ idxf,
    float* __restrict__ counts, float* __restrict__ lossAcc) {
    __shared__ int   sIdx[256];
    __shared__ float wsum[4];
    const int tid = threadIdx.x;
    const int r   = blockIdx.x * 256 + tid;

    int n; float dist;
    if (flags[r]) {
        unsigned long long k = keys[r];
        n = (int)(unsigned)(k & 0xffffffffu);
        float kv = __uint_as_float((unsigned)(k >> 32));
        dist = x2[r] + 2.0f * kv;          // x2 + e2 - 2 x.e
    } else {
        n = provIdx[r];
        dist = x2[r] - 2.0f * gBest[r];
    }
    sIdx[tid] = n;
    idxf[r]   = (float)n;
    atomicAdd(&counts[n], 1.0f);

    float ls = dist;
#pragma unroll
    for (int off = 32; off >= 1; off >>= 1) ls += __shfl_xor(ls, off, 64);
    if ((tid & 63) == 0) wsum[tid >> 6] = ls;
    __syncthreads();
    if (tid == 0) atomicAdd(lossAcc, wsum[0] + wsum[1] + wsum[2] + wsum[3]);

    const float4* cb4 = (const float4*)cb;
    float4* zq4 = (float4*)(zq + (size_t)blockIdx.x * 256 * DIM);
    for (int t = tid; t < 256 * (DIM / 4); t += 256) {
        int row = t >> 7, f4 = t & 127;
        zq4[(size_t)row * 128 + f4] = cb4[(size_t)sIdx[row] * 128 + f4];
    }
}

// ---------------------------------------------------------------------------
// Kernel 6: finalize scalars
// ---------------------------------------------------------------------------
__global__ __launch_bounds__(256) void vq_finalize(const float* __restrict__ counts,
                                                   const float* __restrict__ lossAcc,
                                                   float* __restrict__ out_loss,
                                                   float* __restrict__ out_perp) {
    __shared__ float wsum[4];
    int tid = threadIdx.x;
    float s = 0.0f;
    for (int i = tid; i < K_CODES; i += 256) {
        float p = counts[i] * (1.0f / (float)N_VEC);
        s += p * logf(p + 1e-10f);
    }
#pragma unroll
    for (int off = 32; off >= 1; off >>= 1) s += __shfl_xor(s, off, 64);
    if ((tid & 63) == 0) wsum[tid >> 6] = s;
    __syncthreads();
    if (tid == 0) {
        *out_perp = expf(-(wsum[0] + wsum[1] + wsum[2] + wsum[3]));
        *out_loss = 1.25f * lossAcc[0] / (float)(N_VEC * DIM);
    }
}

// ---------------------------------------------------------------------------
// ws layout (bytes), total ~44.6 MB (unchanged):
//   x2 @0 131072 | hne2 @131072 32768 | counts @163840 32768 | lossAcc @196608 4
//   rescueCnt @196612 4 | pairCnt @196616 4 | provIdx @262144 131072
//   flags @393216 131072 | keys @524288 262144 | rescueRows @786432 131072
//   pG @1048576 524288 | pN @1572864 524288 | pG2 @2097152 524288
//   zh @2621440 33554432 | ch @36175872 8388608
// Scratch in d_out's zq region (consumed by scan/pair BEFORE vq_final
// overwrites zq; stream-ordered, safe):
//   pN2 @out+0 524288 | pG3 @out+524288 524288
//   mergedN2 @out+1048576 131072 | pairRows @out+1179648 131072
// ---------------------------------------------------------------------------
extern "C" void kernel_launch(void* const* d_in, const int* in_sizes, int n_in,
                              void* d_out, int out_size, void* d_ws, size_t ws_size,
                              hipStream_t stream) {
    (void)in_sizes; (void)n_in; (void)out_size; (void)ws_size;
    const float* z  = (const float*)d_in[0];
    const float* cb = (const float*)d_in[1];

    char* ws = (char*)d_ws;
    float* x2        = (float*)(ws + 0);
    float* hne2      = (float*)(ws + 131072);
    float* counts    = (float*)(ws + 163840);
    float* lossAcc   = (float*)(ws + 196608);
    int*   rescueCnt = (int*)  (ws + 196612);
    int*   pairCnt   = (int*)  (ws + 196616);
    int*   provIdx   = (int*)  (ws + 262144);
    int*   flags     = (int*)  (ws + 393216);
    unsigned long long* keys = (unsigned long long*)(ws + 524288);
    int*   rescueRows = (int*) (ws + 786432);
    float* pG        = (float*)(ws + 1048576);
    int*   pN        = (int*)  (ws + 1572864);
    float* pG2       = (float*)(ws + 2097152);
    unsigned short* zh = (unsigned short*)(ws + 2621440);
    unsigned short* ch = (unsigned short*)(ws + 36175872);

    float* out      = (float*)d_out;
    float* zq       = out;
    float* out_loss = out + 16777216;
    float* idxf     = out + 16777217;
    float* out_perp = out + 16777217 + 32768;

    // scratch inside zq region (dead before vq_final writes zq)
    char* sc = (char*)d_out;
    int*   pN2      = (int*)  (sc + 0);
    float* pG3      = (float*)(sc + 524288);
    int*   mergedN2 = (int*)  (sc + 1048576);
    int*   pairRows = (int*)  (sc + 1179648);

    // zero counts + lossAcc + rescueCnt + pairCnt (contiguous) and rescueRows
    hipMemsetAsync(counts, 0, 32768 + 16, stream);
    hipMemsetAsync(rescueRows, 0, 131072, stream);
    vq_prep<<<(N_VEC + K_CODES) / 4, 256, 0, stream>>>(z, cb, x2, hne2, zh, ch);
    dim3 grid(N_VEC / 128, 2);
    vq_gemm<<<grid, 256, 0, stream>>>(zh, ch, hne2, pG, pN, pG2, pN2, pG3);
    vq_scan<<<N_VEC / 256, 256, 0, stream>>>(pG, pN, pG2, pN2, pG3, provIdx, flags,
                                             keys, rescueRows, rescueCnt,
                                             pairRows, pairCnt, mergedN2);
    vq_pair<<<128, 256, 0, stream>>>(z, cb, hne2, provIdx, mergedN2,
                                     pairRows, pairCnt, keys);
    dim3 rgrid(32, 32);
    vq_rescue<<<rgrid, 256, 0, stream>>>(z, cb, hne2, rescueRows, rescueCnt, keys);
    vq_final<<<N_VEC / 256, 256, 0, stream>>>(pG, provIdx, flags, keys, x2, cb,
                                              zq, idxf, counts, lossAcc);
    vq_finalize<<<1, 256, 0, stream>>>(counts, lossAcc, out_loss, out_perp);
}